// Round 20
// baseline (561.774 us; speedup 1.0000x reference)
//
#include <hip/hip_runtime.h>

typedef __attribute__((ext_vector_type(8))) short short8;
typedef __attribute__((ext_vector_type(8))) unsigned short ushort8;
typedef __attribute__((ext_vector_type(4))) float f32x4;

#define B_   32
#define L_   8192
#define IN_  512
#define HID_ 512
#define D3_  128
#define BL_  (B_ * L_)

static __device__ __forceinline__ short f2bf(float f) {
    return __builtin_bit_cast(short, (__bf16)f);
}
static __device__ __forceinline__ unsigned short f2bfu(float f) {
    return __builtin_bit_cast(unsigned short, (__bf16)f);
}

// ---- prep: Wh (f32, D3 x HID) -> bf16, PRE-PERMUTED to MFMA lane order ----
// unit u = ks*512 + nt*64 + lane holds Wh[nt*16+(lane&15)][ks*32+(lane>>4)*8 ..+8]
// == exactly the 16B lane `lane` needs as the B-operand of (step ks, col-blk nt).
__global__ void prep_whb2(const float* __restrict__ wh, unsigned short* __restrict__ whb2) {
    int u = blockIdx.x * 256 + threadIdx.x;   // 0..8191 (16B units)
    int lane = u & 63;
    int nt   = (u >> 6) & 7;
    int ks   = u >> 9;
    int col  = nt * 16 + (lane & 15);
    int k0   = ks * 32 + (lane >> 4) * 8;
    const float* src = wh + col * HID_ + k0;
    float4 a = *(const float4*)(src);
    float4 b = *(const float4*)(src + 4);
    unsigned short* d = whb2 + (size_t)u * 8;
    d[0] = f2bfu(a.x); d[1] = f2bfu(a.y); d[2] = f2bfu(a.z); d[3] = f2bfu(a.w);
    d[4] = f2bfu(b.x); d[5] = f2bfu(b.y); d[6] = f2bfu(b.z); d[7] = f2bfu(b.w);
}

// ---- prep: qpb[b][d] = inputs[b] . Wi[d] + bi[d] + bh[d]  (fp32) ----
__global__ void prep_qpb(const float* __restrict__ inputs, const float* __restrict__ Wi,
                         const float* __restrict__ bi, const float* __restrict__ bh,
                         float* __restrict__ qpb) {
    int b = blockIdx.x;
    int d = threadIdx.x;                 // 128 threads
    float acc = bi[d] + bh[d];
    const float* xr = inputs + b * IN_;
    const float* wr = Wi + d * IN_;
    #pragma unroll 4
    for (int i = 0; i < IN_; i += 4) {
        float4 x = *(const float4*)(xr + i);
        float4 w = *(const float4*)(wr + i);
        acc += x.x * w.x + x.y * w.y + x.z * w.z + x.w * w.w;
    }
    qpb[b * D3_ + d] = acc;
}

// ---- main ----
// The clean 16-waves/CU test (R19 minus traffic-doubling, R15 minus the
// 64-VGPR trap): ZERO LDS -> two 512-thread blocks co-reside (m69: 128
// VGPR => 16 waves/CU). B-frags load lane-linear from the permuted whb2
// in L2 (128 KiB, replicated per-XCD; 16 waves read identical addresses
// -> mostly L1 hits). Context read ONCE (single traffic). Zero barriers.
// vmcnt ordering: B loads issue BEFORE the A-ring refill each step --
// vmcnt retires in order, so the MFMA's wait-for-B (vmcnt(2)) does not
// force the freshly-issued A(KK+2) HBM loads to land; A keeps its 2-step
// prefetch distance. Step-end sched_barrier(0) stops cross-step B-hoist
// (spill guard). Budget: acc 32 + ring 16 + B 32 + aA 4 + addr ~14 < 128.
__global__ __launch_bounds__(512) void attn_main(
    const float* __restrict__ ctx, const unsigned short* __restrict__ whb2,
    const float* __restrict__ qpb, const float* __restrict__ V,
    float* __restrict__ out)
{
    const int tid  = threadIdx.x;
    const int lane = tid & 63;
    const int w    = tid >> 6;           // wave 0..7, owns 16 rows per tile
    const int cb   = lane & 15;          // A-row / C-col index
    const int g    = lane >> 4;          // k-group 0..3

    // B-read base in L2 (lane-linear: the permuted layout IS the lane order)
    const char* bptr = (const char*)whb2 + lane * 16;

    // A stream: lane (cb,g) reads row (base+cb), floats [kk*32 + g*8, +8)
    const float* pL = ctx + ((size_t)blockIdx.x * 512 + w * 16 + cb) * (size_t)HID_ + g * 8;

    const int b = blockIdx.x >> 4;       // 512 rows/block, 16 blocks per batch item

// one K-step: (1) 8 B-loads (L2/L1) FIRST, (2) A-ring refill (HBM), (3) cvt,
// (4) 8 MFMAs (compiler waits vmcnt(2) = b7; the newer A loads stay in
// flight). Step-end sched_barrier(0) pins the boundary.
#define DOSTEP(PA, PB, KK) { \
    const char* bp_ = bptr + (KK) * 8192; \
    const short8 b0 = *(const short8*)(bp_); \
    const short8 b1 = *(const short8*)(bp_ + 1024); \
    const short8 b2 = *(const short8*)(bp_ + 2048); \
    const short8 b3 = *(const short8*)(bp_ + 3072); \
    const short8 b4 = *(const short8*)(bp_ + 4096); \
    const short8 b5 = *(const short8*)(bp_ + 5120); \
    const short8 b6 = *(const short8*)(bp_ + 6144); \
    const short8 b7 = *(const short8*)(bp_ + 7168); \
    short8 aA; \
    aA[0] = f2bf(PA.x); aA[1] = f2bf(PA.y); aA[2] = f2bf(PA.z); aA[3] = f2bf(PA.w); \
    aA[4] = f2bf(PB.x); aA[5] = f2bf(PB.y); aA[6] = f2bf(PB.z); aA[7] = f2bf(PB.w); \
    if ((KK) < 14) { \
        PA = *(const float4*)(pT + ((KK) + 2) * 32); \
        PB = *(const float4*)(pT + ((KK) + 2) * 32 + 4); \
    } else { \
        PA = *(const float4*)(pN + ((KK) - 14) * 32); \
        PB = *(const float4*)(pN + ((KK) - 14) * 32 + 4); \
    } \
    acc[0] = __builtin_amdgcn_mfma_f32_16x16x32_bf16(aA, b0, acc[0], 0, 0, 0); \
    acc[1] = __builtin_amdgcn_mfma_f32_16x16x32_bf16(aA, b1, acc[1], 0, 0, 0); \
    acc[2] = __builtin_amdgcn_mfma_f32_16x16x32_bf16(aA, b2, acc[2], 0, 0, 0); \
    acc[3] = __builtin_amdgcn_mfma_f32_16x16x32_bf16(aA, b3, acc[3], 0, 0, 0); \
    acc[4] = __builtin_amdgcn_mfma_f32_16x16x32_bf16(aA, b4, acc[4], 0, 0, 0); \
    acc[5] = __builtin_amdgcn_mfma_f32_16x16x32_bf16(aA, b5, acc[5], 0, 0, 0); \
    acc[6] = __builtin_amdgcn_mfma_f32_16x16x32_bf16(aA, b6, acc[6], 0, 0, 0); \
    acc[7] = __builtin_amdgcn_mfma_f32_16x16x32_bf16(aA, b7, acc[7], 0, 0, 0); \
    __builtin_amdgcn_sched_barrier(0); }

    // prologue: A for steps 0 and 1 of tile 0
    float4 E0 = *(const float4*)(pL);        float4 E1 = *(const float4*)(pL + 4);
    float4 O0 = *(const float4*)(pL + 32);   float4 O1 = *(const float4*)(pL + 36);

    #pragma unroll 1
    for (int t = 0; t < 4; ++t) {        // 4 tiles of 128 rows (8 waves x 16)
        const float* pT = pL + (size_t)t * (128 * HID_);
        const float* pN = (t < 3) ? (pT + 128 * HID_) : pL;   // clamp: warm re-read

        f32x4 acc[8];
        #pragma unroll
        for (int nt = 0; nt < 8; ++nt) acc[nt] = (f32x4){0.f, 0.f, 0.f, 0.f};

        DOSTEP(E0, E1, 0)   DOSTEP(O0, O1, 1)
        DOSTEP(E0, E1, 2)   DOSTEP(O0, O1, 3)
        DOSTEP(E0, E1, 4)   DOSTEP(O0, O1, 5)
        DOSTEP(E0, E1, 6)   DOSTEP(O0, O1, 7)
        DOSTEP(E0, E1, 8)   DOSTEP(O0, O1, 9)
        DOSTEP(E0, E1, 10)  DOSTEP(O0, O1, 11)
        DOSTEP(E0, E1, 12)  DOSTEP(O0, O1, 13)
        DOSTEP(E0, E1, 14)  DOSTEP(O0, O1, 15)

        // epilogue: tanh(acc + q) . V, reduce over the 16 cb lanes.
        // qpb/V are L2-hot: loaded here, not held across the main loop.
        float s0 = 0.f, s1 = 0.f, s2 = 0.f, s3 = 0.f;
        #pragma unroll
        for (int nt = 0; nt < 8; ++nt) {
            const float q  = qpb[b * D3_ + nt * 16 + cb];
            const float vn = V[nt * 16 + cb];
            s0 += (1.f - 2.f / (__expf(2.f * (acc[nt][0] + q)) + 1.f)) * vn;
            s1 += (1.f - 2.f / (__expf(2.f * (acc[nt][1] + q)) + 1.f)) * vn;
            s2 += (1.f - 2.f / (__expf(2.f * (acc[nt][2] + q)) + 1.f)) * vn;
            s3 += (1.f - 2.f / (__expf(2.f * (acc[nt][3] + q)) + 1.f)) * vn;
        }
        #pragma unroll
        for (int m = 1; m < 16; m <<= 1) {
            s0 += __shfl_xor(s0, m, 64);
            s1 += __shfl_xor(s1, m, 64);
            s2 += __shfl_xor(s2, m, 64);
            s3 += __shfl_xor(s3, m, 64);
        }
        if (cb == 0) {
            const size_t row0 = (size_t)blockIdx.x * 512 + (size_t)t * 128 + w * 16;
            const size_t off_ = row0 + (size_t)g * 4;
            *(float4*)(out + off_) = make_float4(s0, s1, s2, s3);
            *(float4*)(out + (size_t)BL_ + off_) = make_float4(1.f, 1.f, 1.f, 1.f);
        }
    }
#undef DOSTEP
}

extern "C" void kernel_launch(void* const* d_in, const int* in_sizes, int n_in,
                              void* d_out, int out_size, void* d_ws, size_t ws_size,
                              hipStream_t stream) {
    const float* inputs  = (const float*)d_in[0];   // (32, 512)
    const float* context = (const float*)d_in[1];   // (32, 8192, 512)
    const float* Wi      = (const float*)d_in[2];   // (128, 512)
    const float* bi      = (const float*)d_in[3];   // (128,)
    const float* Wh      = (const float*)d_in[4];   // (128, 512)
    const float* bh      = (const float*)d_in[5];   // (128,)
    const float* V       = (const float*)d_in[6];   // (128,)
    float* out = (float*)d_out;                     // [att_row 262144][att 262144]

    unsigned short* whb2 = (unsigned short*)d_ws;                  // 128 KiB (permuted)
    float* qpb = (float*)((char*)d_ws + (size_t)D3_ * HID_ * 2);   // 16 KiB

    prep_whb2<<<32, 256, 0, stream>>>(Wh, whb2);
    prep_qpb<<<B_, D3_, 0, stream>>>(inputs, Wi, bi, bh, qpb);
    attn_main<<<512, 512, 0, stream>>>(context, whb2, qpb, V, out);
}

// Round 21
// 124.283 us; speedup vs baseline: 4.5201x; 4.5201x over previous
//
#include <hip/hip_runtime.h>

typedef __attribute__((ext_vector_type(8))) short short8;
typedef __attribute__((ext_vector_type(8))) unsigned short ushort8;
typedef __attribute__((ext_vector_type(4))) float f32x4;

#define B_   32
#define L_   8192
#define IN_  512
#define HID_ 512
#define D3_  128

static __device__ __forceinline__ short f2bf(float f) {
    return __builtin_bit_cast(short, (__bf16)f);
}
static __device__ __forceinline__ unsigned short f2bfu(float f) {
    return __builtin_bit_cast(unsigned short, (__bf16)f);
}

// async global->LDS, 16B per lane (dest = wave-uniform base + lane*16; the
// global SOURCE is per-lane -- R6-validated idiom)
static __device__ __forceinline__ void gload_lds16(const void* g, void* l) {
    __builtin_amdgcn_global_load_lds(
        (const __attribute__((address_space(1))) unsigned int*)g,
        (__attribute__((address_space(3))) unsigned int*)l, 16, 0, 0);
}

// ---- prep: Wh (f32, D3 x HID) -> bf16, PRE-PERMUTED to MFMA lane order ----
__global__ void prep_whb2(const float* __restrict__ wh, unsigned short* __restrict__ whb2) {
    int u = blockIdx.x * 256 + threadIdx.x;   // 0..8191 (16B units)
    int lane = u & 63;
    int nt   = (u >> 6) & 7;
    int ks   = u >> 9;
    int col  = nt * 16 + (lane & 15);
    int k0   = ks * 32 + (lane >> 4) * 8;
    const float* src = wh + col * HID_ + k0;
    float4 a = *(const float4*)(src);
    float4 b = *(const float4*)(src + 4);
    unsigned short* d = whb2 + (size_t)u * 8;
    d[0] = f2bfu(a.x); d[1] = f2bfu(a.y); d[2] = f2bfu(a.z); d[3] = f2bfu(a.w);
    d[4] = f2bfu(b.x); d[5] = f2bfu(b.y); d[6] = f2bfu(b.z); d[7] = f2bfu(b.w);
}

// ---- prep: qpb[b][d] = inputs[b] . Wi[d] + bi[d] + bh[d]  (fp32) ----
__global__ void prep_qpb(const float* __restrict__ inputs, const float* __restrict__ Wi,
                         const float* __restrict__ bi, const float* __restrict__ bh,
                         float* __restrict__ qpb) {
    int b = blockIdx.x;
    int d = threadIdx.x;                 // 128 threads
    float acc = bi[d] + bh[d];
    const float* xr = inputs + b * IN_;
    const float* wr = Wi + d * IN_;
    #pragma unroll 4
    for (int i = 0; i < IN_; i += 4) {
        float4 x = *(const float4*)(xr + i);
        float4 w = *(const float4*)(wr + i);
        acc += x.x * w.x + x.y * w.y + x.z * w.z + x.w * w.w;
    }
    qpb[b * D3_ + d] = acc;
}

// ---- main ----
// FINAL (best of 14 structural variants, R14 = 124.55 us):
// DMA-to-LDS A transport (wave-private double-buffered chunks, zero
// barriers), sector-dense per-lane DMA source, stage-at-step-top, B-frag
// ds_reads hoisted above the vmcnt wait, lane-linear conflict-free whs,
// no register prefetch state -> no spill at the 128-VGPR cap.
__global__ __launch_bounds__(512) void attn_main(
    const float* __restrict__ ctx, const unsigned short* __restrict__ whb2,
    const float* __restrict__ qpb, const float* __restrict__ V,
    float* __restrict__ out)
{
    __shared__ unsigned short whs[D3_ * HID_];   // 128 KiB: [ks 16][nt 8][1024B]
    __shared__ float cbuf[2][4096];              // 32 KiB: [par][wave 8][2048B]

    const int tid = threadIdx.x;

    // stage whs: pure linear copy (whb2 already permuted) -- conflict-free
    #pragma unroll
    for (int p = 0; p < 16; ++p) {
        int m = p * 512 + tid;
        *(ushort8*)((char*)whs + (size_t)m * 16) = *(const ushort8*)(whb2 + (size_t)m * 8);
    }
    __syncthreads();

    const int lane = tid & 63;
    const int w    = tid >> 6;           // wave 0..7, owns 16 rows per tile
    const int cb   = lane & 15;          // A-row / C-col index
    const int g    = lane >> 4;          // k-group 0..3

    // B-read base (lane-linear, conflict-free)
    const char* bptr = (const char*)whs + lane * 16;

    // A DMA: sector-dense per-lane source; lane-linear LDS dest
    const int srow = lane >> 3;                      // row-in-8 this lane sources
    const int spce = (lane & 7) ^ srow;              // piece (16B) within 128B
    const float* gsrcA = ctx
        + ((size_t)blockIdx.x * 1024 + w * 16 + srow) * (size_t)HID_ + spce * 4;
    const float* gsrcB = gsrcA + 8 * HID_;           // rows 8..15
    char* ldst = (char*)cbuf + w * 2048 + lane * 16;

    // A-read: row cb, pieces 2g / 2g+1, through the baked XOR
    const char* abase = (const char*)cbuf + w * 2048 + (cb >> 3) * 1024 + (cb & 7) * 128;
    const int aoff0 = (((2 * g)     ^ (cb & 7)) << 4);
    const int aoff1 = (((2 * g + 1) ^ (cb & 7)) << 4);

    const int b = blockIdx.x >> 3;       // 1024 rows per block, 8 blocks per batch

    float vv[8], qv[8];
    #pragma unroll
    for (int nt = 0; nt < 8; ++nt) {
        vv[nt] = V[nt * 16 + cb];
        qv[nt] = qpb[b * D3_ + nt * 16 + cb];
    }

#define STAGE(CC) { \
    const size_t go_ = (size_t)((CC) >> 4) * (128 * HID_) + ((CC) & 15) * 32; \
    char* l0_ = ldst + (((CC) & 1) ? 16384 : 0); \
    gload_lds16(gsrcA + go_, l0_); \
    gload_lds16(gsrcB + go_, l0_ + 1024); }

    STAGE(0)
    STAGE(1)

    #pragma unroll 1
    for (int t = 0; t < 8; ++t) {        // 8 tiles of 128 rows
        f32x4 acc[8];
        #pragma unroll
        for (int nt = 0; nt < 8; ++nt) acc[nt] = (f32x4){0.f, 0.f, 0.f, 0.f};

        #pragma unroll
        for (int kk = 0; kk < 16; ++kk) {
            const int c = t * 16 + kk;

            // (1) B-frag preload: 8 ds_read_b128 issued BEFORE the HBM wait,
            // so the LDS pipe works during the vmcnt stall. whs is read-only.
            short8 bb[8];
            {
                const char* bp = bptr + kk * 8192;
                #pragma unroll
                for (int nt = 0; nt < 8; ++nt)
                    bb[nt] = *(const short8*)(bp + nt * 1024);
            }

            // (2) wait for A chunk c (DMA completion invisible to compiler)
            if (c < 127) asm volatile("s_waitcnt vmcnt(2)" ::: "memory");
            else         asm volatile("s_waitcnt vmcnt(0)" ::: "memory");

            // (3) A-reads of the buffer that chunk c+2 will overwrite
            const char* ap = abase + ((c & 1) ? 16384 : 0);
            const f32x4 a0 = *(const f32x4*)(ap + aoff0);   // pieces 2g
            const f32x4 a1 = *(const f32x4*)(ap + aoff1);   // pieces 2g+1
            // (4) drain LDS reads, then (5) re-stage this buffer immediately
            asm volatile("s_waitcnt lgkmcnt(0)" ::: "memory");
            __builtin_amdgcn_sched_barrier(0);
            if (c + 2 < 128) STAGE(c + 2)
            __builtin_amdgcn_sched_barrier(0);

            // (6) convert + MFMAs (B already in regs)
            short8 aA;
            aA[0] = f2bf(a0[0]); aA[1] = f2bf(a0[1]); aA[2] = f2bf(a0[2]); aA[3] = f2bf(a0[3]);
            aA[4] = f2bf(a1[0]); aA[5] = f2bf(a1[1]); aA[6] = f2bf(a1[2]); aA[7] = f2bf(a1[3]);

            #pragma unroll
            for (int nt = 0; nt < 8; ++nt)
                acc[nt] = __builtin_amdgcn_mfma_f32_16x16x32_bf16(aA, bb[nt], acc[nt], 0, 0, 0);

            if (kk == 15) {
                // epilogue: tanh(acc + q) . V, reduce over the 16 cb lanes
                float s0 = 0.f, s1 = 0.f, s2 = 0.f, s3 = 0.f;
                #pragma unroll
                for (int nt = 0; nt < 8; ++nt) {
                    const float q = qv[nt], vn = vv[nt];
                    s0 += (1.f - 2.f / (__expf(2.f * (acc[nt][0] + q)) + 1.f)) * vn;
                    s1 += (1.f - 2.f / (__expf(2.f * (acc[nt][1] + q)) + 1.f)) * vn;
                    s2 += (1.f - 2.f / (__expf(2.f * (acc[nt][2] + q)) + 1.f)) * vn;
                    s3 += (1.f - 2.f / (__expf(2.f * (acc[nt][3] + q)) + 1.f)) * vn;
                }
                #pragma unroll
                for (int m = 1; m < 16; m <<= 1) {
                    s0 += __shfl_xor(s0, m, 64);
                    s1 += __shfl_xor(s1, m, 64);
                    s2 += __shfl_xor(s2, m, 64);
                    s3 += __shfl_xor(s3, m, 64);
                }
                if (cb == 0) {
                    const size_t row0 = (size_t)blockIdx.x * 1024 + (size_t)t * 128 + w * 16;
                    const size_t off_ = row0 + (size_t)g * 4;
                    *(float4*)(out + off_) = make_float4(s0, s1, s2, s3);
                    *(float4*)(out + (size_t)B_ * L_ + off_) = make_float4(1.f, 1.f, 1.f, 1.f);
                }
            }
        }
    }
#undef STAGE
}

extern "C" void kernel_launch(void* const* d_in, const int* in_sizes, int n_in,
                              void* d_out, int out_size, void* d_ws, size_t ws_size,
                              hipStream_t stream) {
    const float* inputs  = (const float*)d_in[0];   // (32, 512)
    const float* context = (const float*)d_in[1];   // (32, 8192, 512)
    const float* Wi      = (const float*)d_in[2];   // (128, 512)
    const float* bi      = (const float*)d_in[3];   // (128,)
    const float* Wh      = (const float*)d_in[4];   // (128, 512)
    const float* bh      = (const float*)d_in[5];   // (128,)
    const float* V       = (const float*)d_in[6];   // (128,)
    float* out = (float*)d_out;                     // [att_row 262144][att 262144]

    unsigned short* whb2 = (unsigned short*)d_ws;                  // 128 KiB (permuted)
    float* qpb = (float*)((char*)d_ws + (size_t)D3_ * HID_ * 2);   // 16 KiB

    prep_whb2<<<32, 256, 0, stream>>>(Wh, whb2);
    prep_qpb<<<B_, D3_, 0, stream>>>(inputs, Wi, bi, bh, qpb);
    attn_main<<<256, 512, 0, stream>>>(context, whb2, qpb, V, out);
}